// Round 17
// baseline (132.724 us; speedup 1.0000x reference)
//
#include <hip/hip_runtime.h>
#include <math.h>

#define D      4096
#define NPREV  8191
#define NROWS  8192
#define FBL    2048         // flash blocks
#define FRL    4            // rows per flash block
#define PFB    128          // W_V prefetch blocks appended to flash grid

typedef float f4 __attribute__((ext_vector_type(4)));

static __device__ __forceinline__ void nt_store4(f4 v, float* p) {
    __builtin_nontemporal_store(v, reinterpret_cast<f4*>(p));
}
static __device__ __forceinline__ f4 ld4(const float* p) {
    return *reinterpret_cast<const f4*>(p);
}
static __device__ __forceinline__ void st4(f4 v, float* p) {
    *reinterpret_cast<f4*>(p) = v;
}

// ---- K1: fused q + kq-partial. 256 blocks x 256 -----------------------------
// Block b owns rows m in [16b, 16b+16): phase 1 computes q[m] (wave-per-row
// dot vs LDS-staged inp), phase 2 accumulates partial kq = sum q[m]*W_K[m,:].
__global__ void k_qkq(const float* __restrict__ W_Q, const float* __restrict__ W_K,
                      const float* __restrict__ inp, float* __restrict__ kqpart) {
    __shared__ f4 s_inp[1024];          // 16 KB
    __shared__ float s_q[16];
    int t = threadIdx.x, b = blockIdx.x;
    int wid = t >> 6, lane = t & 63;
    for (int i = t; i < 1024; i += 256) s_inp[i] = ld4(inp + 4 * i);
    __syncthreads();
    #pragma unroll
    for (int j = 0; j < 4; ++j) {       // phase 1: 4 rows per wave
        int r = 4 * wid + j;
        const float* Wrow = W_Q + (size_t)(16 * b + r) * D;
        float acc = 0.f;
        #pragma unroll
        for (int i = 0; i < 16; ++i) {
            int c = lane + 64 * i;
            f4 w = ld4(Wrow + 4 * c);
            f4 x = s_inp[c];
            acc += w.x * x.x + w.y * x.y + w.z * x.z + w.w * x.w;
        }
        #pragma unroll
        for (int off = 32; off; off >>= 1) acc += __shfl_down(acc, off, 64);
        if (lane == 0) s_q[r] = acc;
    }
    __syncthreads();
    f4 a0 = (f4)0.f, a1 = a0, a2 = a0, a3 = a0;   // phase 2: kq partial
    #pragma unroll
    for (int r = 0; r < 16; ++r) {
        const float* Wrow = W_K + (size_t)(16 * b + r) * D;
        float qm = s_q[r];
        a0 += qm * ld4(Wrow + 4 * t);
        a1 += qm * ld4(Wrow + 4 * (t + 256));
        a2 += qm * ld4(Wrow + 4 * (t + 512));
        a3 += qm * ld4(Wrow + 4 * (t + 768));
    }
    float* kp = kqpart + (size_t)b * D;
    st4(a0, kp + 4 * t);          st4(a1, kp + 4 * (t + 256));
    st4(a2, kp + 4 * (t + 512));  st4(a3, kp + 4 * (t + 768));
}

// ---- K2: kq[d] = sum over 256 partials. 16 blocks x 256 ---------------------
__global__ void k_kqred(const float* __restrict__ kqpart, float* __restrict__ kq) {
    int d = blockIdx.x * 256 + threadIdx.x;
    float a0 = 0.f, a1 = 0.f, a2 = 0.f, a3 = 0.f;
    for (int p = 0; p < 256; p += 4) {       // 4 independent chains
        a0 += kqpart[(size_t)p * D + d];
        a1 += kqpart[(size_t)(p + 1) * D + d];
        a2 += kqpart[(size_t)(p + 2) * D + d];
        a3 += kqpart[(size_t)(p + 3) * D + d];
    }
    kq[d] = (a0 + a1) + (a2 + a3);
}

// ---- K3: R10-proven LDS flash + W_V L3-prefetch role ------------------------
// Blocks [0,FBL): flash (thread t owns f4 column t; 4-row tile in LDS).
// Blocks [FBL, FBL+PFB): stream-read W_V with caching loads to warm L3.
__global__ __launch_bounds__(1024, 8) void k_flash_lds(
        const float* __restrict__ prev, const float* __restrict__ inp,
        const float* __restrict__ kq, float* __restrict__ io,
        float* __restrict__ ms, float* __restrict__ ctxpart,
        const float* __restrict__ W_V, float* __restrict__ sink) {
    if ((int)blockIdx.x >= FBL) {
        int pb = (int)blockIdx.x - FBL;
        f4 s = (f4)0.f;
        for (size_t i = (size_t)pb * 1024 + threadIdx.x;
             i < (size_t)D * (D / 4); i += (size_t)PFB * 1024)
            s += ld4(W_V + 4 * i);
        float v = s.x + s.y + s.z + s.w;
        if (v > 1e30f) sink[threadIdx.x] = v;   // keeps loads live; never taken
        return;
    }
    __shared__ f4 s_x[FRL][1024];       // 64 KB
    __shared__ float s_wred[16][FRL];
    __shared__ float s_log[FRL];
    const int n0 = blockIdx.x * FRL;
    const int t = threadIdx.x;
    const int wid = t >> 6, lane = t & 63;
    const f4 kqv = ld4(kq + 4 * t);

    f4 x[FRL];
    #pragma unroll
    for (int r = 0; r < FRL; ++r) {
        int n = n0 + r;
        const float* src = (n < NPREV) ? (prev + (size_t)n * D) : inp;
        x[r] = ld4(src + 4 * t);
    }
    float p[FRL];
    #pragma unroll
    for (int r = 0; r < FRL; ++r) {
        int n = n0 + r;
        nt_store4(x[r], io + (size_t)n * D + 4 * t);
        s_x[r][t] = x[r];
        p[r] = x[r].x * kqv.x + x[r].y * kqv.y + x[r].z * kqv.z + x[r].w * kqv.w;
    }
    #pragma unroll
    for (int r = 0; r < FRL; ++r) {
        float v = p[r];
        #pragma unroll
        for (int off = 32; off; off >>= 1) v += __shfl_down(v, off, 64);
        if (lane == 0) s_wred[wid][r] = v;
    }
    __syncthreads();
    if (t < FRL) {
        float s = 0.f;
        #pragma unroll
        for (int w = 0; w < 16; ++w) s += s_wred[w][t];
        s_log[t] = s;
    }
    __syncthreads();
    float m_b = -INFINITY;
    #pragma unroll
    for (int r = 0; r < FRL; ++r) m_b = fmaxf(m_b, s_log[r]);
    float e[FRL], s_b = 0.f;
    #pragma unroll
    for (int r = 0; r < FRL; ++r) { e[r] = __expf(s_log[r] - m_b); s_b += e[r]; }
    f4 a = (f4)0.f;
    #pragma unroll
    for (int r = 0; r < FRL; ++r) a += e[r] * s_x[r][t];
    st4(a, ctxpart + (size_t)blockIdx.x * D + 4 * t);
    if (t == 0) { ms[2 * blockIdx.x] = m_b; ms[2 * blockIdx.x + 1] = s_b; }
}

// ---- K4: combine FBT partials -> normalized ctx. 64 blocks x 256 ------------
template<int FBT>
__global__ void k_combine(const float* __restrict__ ms, const float* __restrict__ ctxpart,
                          float* __restrict__ ctx) {
    constexpr int PPT = FBT / 256;
    constexpr int PPG = FBT / 16;
    __shared__ float s_w[FBT];
    __shared__ float s_red[8];
    __shared__ f4 s_acc[16][16];
    int t = threadIdx.x;
    int lane = t & 63, wid = t >> 6;
    float mloc[PPT];
    float mx = -INFINITY;
    #pragma unroll
    for (int k = 0; k < PPT; ++k) { mloc[k] = ms[2 * (t + 256 * k)]; mx = fmaxf(mx, mloc[k]); }
    #pragma unroll
    for (int off = 32; off; off >>= 1) mx = fmaxf(mx, __shfl_down(mx, off, 64));
    if (lane == 0) s_red[wid] = mx;
    __syncthreads();
    float M = fmaxf(fmaxf(s_red[0], s_red[1]), fmaxf(s_red[2], s_red[3]));
    float sc = 0.f;
    #pragma unroll
    for (int k = 0; k < PPT; ++k) {
        float w = __expf(mloc[k] - M);
        s_w[t + 256 * k] = w;
        sc += w * ms[2 * (t + 256 * k) + 1];
    }
    #pragma unroll
    for (int off = 32; off; off >>= 1) sc += __shfl_down(sc, off, 64);
    if (lane == 0) s_red[4 + wid] = sc;
    __syncthreads();
    float S = s_red[4] + s_red[5] + s_red[6] + s_red[7];
    int c = t & 15, g = t >> 4;
    int col4 = blockIdx.x * 16 + c;
    f4 a = (f4)0.f;
    #pragma unroll 8
    for (int i = 0; i < PPG; ++i) {
        int pp = g * PPG + i;
        a += s_w[pp] * ld4(ctxpart + (size_t)pp * D + 4 * col4);
    }
    s_acc[g][c] = a;
    __syncthreads();
    if (t < 16) {
        f4 aa = (f4)0.f;
        #pragma unroll
        for (int gg = 0; gg < 16; ++gg) aa += s_acc[gg][t];
        st4(aa * (1.f / S), ctx + 4 * (blockIdx.x * 16 + t));
    }
}

// ---- K5: out = W_V @ ctx + inp. 1024 blocks x 256; caching loads (L3-hot) ---
__global__ void k_matvec_out(const float* __restrict__ W, const float* __restrict__ v,
                             const float* __restrict__ resid, float* __restrict__ out) {
    int row  = blockIdx.x * 4 + (threadIdx.x >> 6);
    int lane = threadIdx.x & 63;
    const float* Wrow = W + (size_t)row * D;
    float acc = 0.f;
    #pragma unroll
    for (int i = 0; i < 16; ++i) {
        int c = lane + i * 64;
        f4 w = ld4(Wrow + 4 * c);       // regular load: hit L3 from prefetch
        f4 x = ld4(v + 4 * c);
        acc += w.x * x.x + w.y * x.y + w.z * x.z + w.w * x.w;
    }
    #pragma unroll
    for (int off = 32; off; off >>= 1) acc += __shfl_down(acc, off, 64);
    if (lane == 0) out[row] = acc + resid[row];
}

extern "C" void kernel_launch(void* const* d_in, const int* in_sizes, int n_in,
                              void* d_out, int out_size, void* d_ws, size_t ws_size,
                              hipStream_t stream) {
    const float* prev = (const float*)d_in[0];   // (8191, 4096)
    const float* inp  = (const float*)d_in[1];   // (4096,)
    const float* W_Q  = (const float*)d_in[2];
    const float* W_K  = (const float*)d_in[3];
    const float* W_V  = (const float*)d_in[4];
    float* out = (float*)d_out;                  // [0:4096]=output, [4096:]=inputs
    float* io  = out + D;
    float* ws  = (float*)d_ws;

    // ws: kqpart 256*D | kq D | ms 2*FBL | ctxpart FBL*D | ctx D | sink 1024
    float* kqpart  = ws;
    float* kq      = kqpart + (size_t)256 * D;
    float* ms      = kq + D;
    float* ctxpart = ms + 2 * FBL;
    float* ctx     = ctxpart + (size_t)FBL * D;
    float* sink    = ctx + D;

    k_qkq<<<256, 256, 0, stream>>>(W_Q, W_K, inp, kqpart);
    k_kqred<<<16, 256, 0, stream>>>(kqpart, kq);
    k_flash_lds<<<FBL + PFB, 1024, 0, stream>>>(prev, inp, kq, io, ms, ctxpart,
                                                W_V, sink);
    k_combine<FBL><<<64, 256, 0, stream>>>(ms, ctxpart, ctx);
    k_matvec_out<<<1024, 256, 0, stream>>>(W_V, ctx, inp, out);
}

// Round 18
// 116.098 us; speedup vs baseline: 1.1432x; 1.1432x over previous
//
#include <hip/hip_runtime.h>
#include <math.h>

#define D      4096
#define NPREV  8191
#define NROWS  8192
#define FBL    2048         // flash blocks
#define FRL    4            // rows per flash block

typedef float f4 __attribute__((ext_vector_type(4)));

static __device__ __forceinline__ f4 nt_load4(const float* p) {
    return __builtin_nontemporal_load(reinterpret_cast<const f4*>(p));
}
static __device__ __forceinline__ void nt_store4(f4 v, float* p) {
    __builtin_nontemporal_store(v, reinterpret_cast<f4*>(p));
}
static __device__ __forceinline__ f4 ld4(const float* p) {
    return *reinterpret_cast<const f4*>(p);
}
static __device__ __forceinline__ void st4(f4 v, float* p) {
    *reinterpret_cast<f4*>(p) = v;
}

// ---- K1a: fused q + kq-partial (R17-proven, sans prefetch). 256 blk x 256 ---
__global__ void k_qkq(const float* __restrict__ W_Q, const float* __restrict__ W_K,
                      const float* __restrict__ inp, float* __restrict__ kqpart) {
    __shared__ f4 s_inp[1024];          // 16 KB
    __shared__ float s_q[16];
    int t = threadIdx.x, b = blockIdx.x;
    int wid = t >> 6, lane = t & 63;
    for (int i = t; i < 1024; i += 256) s_inp[i] = ld4(inp + 4 * i);
    __syncthreads();
    #pragma unroll
    for (int j = 0; j < 4; ++j) {       // phase 1: 4 rows per wave
        int r = 4 * wid + j;
        const float* Wrow = W_Q + (size_t)(16 * b + r) * D;
        float acc = 0.f;
        #pragma unroll
        for (int i = 0; i < 16; ++i) {
            int c = lane + 64 * i;
            f4 w = nt_load4(Wrow + 4 * c);
            f4 x = s_inp[c];
            acc += w.x * x.x + w.y * x.y + w.z * x.z + w.w * x.w;
        }
        #pragma unroll
        for (int off = 32; off; off >>= 1) acc += __shfl_down(acc, off, 64);
        if (lane == 0) s_q[r] = acc;
    }
    __syncthreads();
    f4 a0 = (f4)0.f, a1 = a0, a2 = a0, a3 = a0;   // phase 2: kq partial
    #pragma unroll
    for (int r = 0; r < 16; ++r) {
        const float* Wrow = W_K + (size_t)(16 * b + r) * D;
        float qm = s_q[r];
        a0 += qm * nt_load4(Wrow + 4 * t);
        a1 += qm * nt_load4(Wrow + 4 * (t + 256));
        a2 += qm * nt_load4(Wrow + 4 * (t + 512));
        a3 += qm * nt_load4(Wrow + 4 * (t + 768));
    }
    float* kp = kqpart + (size_t)b * D;
    st4(a0, kp + 4 * t);          st4(a1, kp + 4 * (t + 256));
    st4(a2, kp + 4 * (t + 512));  st4(a3, kp + 4 * (t + 768));
}

// ---- K1b: kq[d] = sum over 256 partials. 16 blocks x 256 --------------------
__global__ void k_kqred(const float* __restrict__ kqpart, float* __restrict__ kq) {
    int d = blockIdx.x * 256 + threadIdx.x;
    float a0 = 0.f, a1 = 0.f, a2 = 0.f, a3 = 0.f;
    for (int p = 0; p < 256; p += 4) {
        a0 += kqpart[(size_t)p * D + d];
        a1 += kqpart[(size_t)(p + 1) * D + d];
        a2 += kqpart[(size_t)(p + 2) * D + d];
        a3 += kqpart[(size_t)(p + 3) * D + d];
    }
    kq[d] = (a0 + a1) + (a2 + a3);
}

// ---- fallback K1/K2 (exact R10 path, used when ws is small) -----------------
template<bool RESIDUAL>
__global__ void k_matvec_rows(const float* __restrict__ W, const float* __restrict__ v,
                              const float* __restrict__ resid, float* __restrict__ out) {
    int row  = blockIdx.x * 4 + (threadIdx.x >> 6);
    int lane = threadIdx.x & 63;
    const float* Wrow = W + (size_t)row * D;
    float acc = 0.f;
    #pragma unroll
    for (int i = 0; i < 16; ++i) {
        int c = lane + i * 64;
        f4 w = nt_load4(Wrow + 4 * c);
        f4 x = ld4(v + 4 * c);
        acc += w.x * x.x + w.y * x.y + w.z * x.z + w.w * x.w;
    }
    #pragma unroll
    for (int off = 32; off; off >>= 1) acc += __shfl_down(acc, off, 64);
    if (lane == 0) out[row] = RESIDUAL ? (acc + resid[row]) : acc;
}

__global__ void k_kq(const float* __restrict__ W, const float* __restrict__ q,
                     float* __restrict__ kq) {
    __shared__ float s_q[D];
    __shared__ f4 s_part[64][4];
    int t = threadIdx.x;
    int b = blockIdx.x;
    for (int i = t; i < D; i += 256) s_q[i] = q[i];
    __syncthreads();
    int c4 = b * 4 + (t & 3);
    int r0 = t >> 2;
    f4 acc = (f4)0.f;
    #pragma unroll 16
    for (int i = 0; i < 64; ++i) {
        int m = r0 + i * 64;
        acc += s_q[m] * nt_load4(W + (size_t)m * D + 4 * c4);
    }
    s_part[r0][t & 3] = acc;
    __syncthreads();
    if (t < 4) {
        f4 a = (f4)0.f;
        #pragma unroll
        for (int g = 0; g < 64; ++g) a += s_part[g][t];
        st4(a, kq + 4 * (b * 4 + t));
    }
}

// ---- K2: R10-proven LDS-resident flash. FBL=2048 x 1024, FRL=4 --------------
__global__ __launch_bounds__(1024, 8) void k_flash_lds(
        const float* __restrict__ prev, const float* __restrict__ inp,
        const float* __restrict__ kq, float* __restrict__ io,
        float* __restrict__ ms, float* __restrict__ ctxpart) {
    __shared__ f4 s_x[FRL][1024];       // 64 KB
    __shared__ float s_wred[16][FRL];
    __shared__ float s_log[FRL];
    const int n0 = blockIdx.x * FRL;
    const int t = threadIdx.x;
    const int wid = t >> 6, lane = t & 63;
    const f4 kqv = ld4(kq + 4 * t);

    f4 x[FRL];
    #pragma unroll
    for (int r = 0; r < FRL; ++r) {
        int n = n0 + r;
        const float* src = (n < NPREV) ? (prev + (size_t)n * D) : inp;
        x[r] = ld4(src + 4 * t);
    }
    float p[FRL];
    #pragma unroll
    for (int r = 0; r < FRL; ++r) {
        int n = n0 + r;
        nt_store4(x[r], io + (size_t)n * D + 4 * t);
        s_x[r][t] = x[r];
        p[r] = x[r].x * kqv.x + x[r].y * kqv.y + x[r].z * kqv.z + x[r].w * kqv.w;
    }
    #pragma unroll
    for (int r = 0; r < FRL; ++r) {
        float v = p[r];
        #pragma unroll
        for (int off = 32; off; off >>= 1) v += __shfl_down(v, off, 64);
        if (lane == 0) s_wred[wid][r] = v;
    }
    __syncthreads();
    if (t < FRL) {
        float s = 0.f;
        #pragma unroll
        for (int w = 0; w < 16; ++w) s += s_wred[w][t];
        s_log[t] = s;
    }
    __syncthreads();
    float m_b = -INFINITY;
    #pragma unroll
    for (int r = 0; r < FRL; ++r) m_b = fmaxf(m_b, s_log[r]);
    float e[FRL], s_b = 0.f;
    #pragma unroll
    for (int r = 0; r < FRL; ++r) { e[r] = __expf(s_log[r] - m_b); s_b += e[r]; }
    f4 a = (f4)0.f;
    #pragma unroll
    for (int r = 0; r < FRL; ++r) a += e[r] * s_x[r][t];
    st4(a, ctxpart + (size_t)blockIdx.x * D + 4 * t);
    if (t == 0) { ms[2 * blockIdx.x] = m_b; ms[2 * blockIdx.x + 1] = s_b; }
}

// ---- K3: combine FBT partials -> normalized ctx. 64 blocks x 256 ------------
template<int FBT>
__global__ void k_combine(const float* __restrict__ ms, const float* __restrict__ ctxpart,
                          float* __restrict__ ctx) {
    constexpr int PPT = FBT / 256;
    constexpr int PPG = FBT / 16;
    __shared__ float s_w[FBT];
    __shared__ float s_red[8];
    __shared__ f4 s_acc[16][16];
    int t = threadIdx.x;
    int lane = t & 63, wid = t >> 6;
    float mloc[PPT];
    float mx = -INFINITY;
    #pragma unroll
    for (int k = 0; k < PPT; ++k) { mloc[k] = ms[2 * (t + 256 * k)]; mx = fmaxf(mx, mloc[k]); }
    #pragma unroll
    for (int off = 32; off; off >>= 1) mx = fmaxf(mx, __shfl_down(mx, off, 64));
    if (lane == 0) s_red[wid] = mx;
    __syncthreads();
    float M = fmaxf(fmaxf(s_red[0], s_red[1]), fmaxf(s_red[2], s_red[3]));
    float sc = 0.f;
    #pragma unroll
    for (int k = 0; k < PPT; ++k) {
        float w = __expf(mloc[k] - M);
        s_w[t + 256 * k] = w;
        sc += w * ms[2 * (t + 256 * k) + 1];
    }
    #pragma unroll
    for (int off = 32; off; off >>= 1) sc += __shfl_down(sc, off, 64);
    if (lane == 0) s_red[4 + wid] = sc;
    __syncthreads();
    float S = s_red[4] + s_red[5] + s_red[6] + s_red[7];
    int c = t & 15, g = t >> 4;
    int col4 = blockIdx.x * 16 + c;
    f4 a = (f4)0.f;
    #pragma unroll 8
    for (int i = 0; i < PPG; ++i) {
        int pp = g * PPG + i;
        a += s_w[pp] * ld4(ctxpart + (size_t)pp * D + 4 * col4);
    }
    s_acc[g][c] = a;
    __syncthreads();
    if (t < 16) {
        f4 aa = (f4)0.f;
        #pragma unroll
        for (int gg = 0; gg < 16; ++gg) aa += s_acc[gg][t];
        st4(aa * (1.f / S), ctx + 4 * (blockIdx.x * 16 + t));
    }
}

extern "C" void kernel_launch(void* const* d_in, const int* in_sizes, int n_in,
                              void* d_out, int out_size, void* d_ws, size_t ws_size,
                              hipStream_t stream) {
    const float* prev = (const float*)d_in[0];   // (8191, 4096)
    const float* inp  = (const float*)d_in[1];   // (4096,)
    const float* W_Q  = (const float*)d_in[2];
    const float* W_K  = (const float*)d_in[3];
    const float* W_V  = (const float*)d_in[4];
    float* out = (float*)d_out;                  // [0:4096]=output, [4096:]=inputs
    float* io  = out + D;
    float* ws  = (float*)d_ws;

    // fused-path ws: kqpart 256*D | kq D | ms 2*FBL | ctxpart FBL*D | ctx D
    size_t need_fused = (size_t)((size_t)256 * D + D + 2 * FBL
                                 + (size_t)FBL * D + D) * sizeof(float);

    if (ws_size >= need_fused) {
        float* kqpart  = ws;
        float* kq      = kqpart + (size_t)256 * D;
        float* ms      = kq + D;
        float* ctxpart = ms + 2 * FBL;
        float* ctx     = ctxpart + (size_t)FBL * D;

        k_qkq<<<256, 256, 0, stream>>>(W_Q, W_K, inp, kqpart);
        k_kqred<<<16, 256, 0, stream>>>(kqpart, kq);
        k_flash_lds<<<FBL, 1024, 0, stream>>>(prev, inp, kq, io, ms, ctxpart);
        k_combine<FBL><<<64, 256, 0, stream>>>(ms, ctxpart, ctx);
        k_matvec_rows<true><<<1024, 256, 0, stream>>>(W_V, ctx, inp, out);
    } else {
        // exact R10 path (proven 112.5 us, ws ~33.6 MB)
        float* q       = ws;
        float* kq      = q + D;
        float* ms      = kq + D;
        float* ctxpart = ms + 2 * FBL;
        float* ctx     = ctxpart + (size_t)FBL * D;

        k_matvec_rows<false><<<1024, 256, 0, stream>>>(W_Q, inp, nullptr, q);
        k_kq<<<256, 256, 0, stream>>>(W_K, q, kq);
        k_flash_lds<<<FBL, 1024, 0, stream>>>(prev, inp, kq, io, ms, ctxpart);
        k_combine<FBL><<<64, 256, 0, stream>>>(ms, ctxpart, ctx);
        k_matvec_rows<true><<<1024, 256, 0, stream>>>(W_V, ctx, inp, out);
    }
}